// Round 4
// baseline (20748.514 us; speedup 1.0000x reference)
//
#include <hip/hip_runtime.h>
#include <hip/hip_bf16.h>

#define S_LEN 512
#define D_IN  64
#define HID   256
#define MLPH  64
#define D_OUT 16

// tanh via exp2-based __expf; clamped so e stays finite. ~8 instrs, no branch.
__device__ __forceinline__ float fast_tanh(float v) {
    float a = fabsf(v);
    float e = __expf(fminf(2.0f * a, 40.0f));
    float r = __fdividef(e - 1.0f, e + 1.0f);
    return copysignf(r, v);
}

// One workgroup (512 thr, 8 waves) per batch element, one CU each.
// Pipeline: iter t computes RNN-main_t (needs h_t, x_t[16:]) OVERLAPPED with
// MLP(h_t)=o_{t-1}; the 16-wide splice dot + tanh close the step. 4 barriers.
// All reductions are same-wave shfl_xor; weights register-resident.
__launch_bounds__(512, 2)
__global__ void rnn_ar_kernel(const float* __restrict__ x,
                              const float* __restrict__ W_ih,
                              const float* __restrict__ b_ih,
                              const float* __restrict__ W_hh,
                              const float* __restrict__ b_hh,
                              const float* __restrict__ W1,
                              const float* __restrict__ b1,
                              const float* __restrict__ W2,
                              const float* __restrict__ b2,
                              const float* __restrict__ W3,
                              const float* __restrict__ b3,
                              const int*   __restrict__ ps_ptr,
                              float* __restrict__ out) {
    const int b   = blockIdx.x;
    const int tid = threadIdx.x;
    const int ps  = *ps_ptr;

    // roles
    const int r  = tid >> 1;          // RNN row (0..255)
    const int q  = tid & 1;           // RNN K-half
    const int m1row = tid >> 3;       // MLP1/2 row (0..63)
    const int m1q   = tid & 7;        // MLP1/2 K-chunk
    const int row3  = tid >> 4;       // MLP3 row (0..15), tid<256
    const int q3    = tid & 15;       // MLP3 K-chunk

    // LDS: s_A[p] = [ x_t[16:64) (48) | h_t (256) ]  contiguous combined vec
    __shared__ float s_A[2][304];
    __shared__ float s_hp[2][8][36];  // padded h copy for MLP1 (stride 36: 16B-aligned, bank-clean)
    __shared__ float s_a1[MLPH];
    __shared__ float s_a2[MLPH];
    __shared__ float s_o[2][16];      // splice zone: x_t[0:16) or o_{t-1}

    // ---- register-resident weights
    // RNN combined K-vector: q=0 -> [x48 | h[0:104)], q=1 -> h[104:256)
    float4 wv[38];
    {
        const float* wih_r = W_ih + (size_t)r * D_IN;
        const float* whh_r = W_hh + (size_t)r * HID;
        if (q == 0) {
            #pragma unroll
            for (int j = 0; j < 12; ++j) wv[j] = *(const float4*)(wih_r + 16 + j * 4);
            #pragma unroll
            for (int j = 0; j < 26; ++j) wv[12 + j] = *(const float4*)(whh_r + j * 4);
        } else {
            #pragma unroll
            for (int j = 0; j < 38; ++j) wv[j] = *(const float4*)(whh_r + 104 + j * 4);
        }
    }
    float4 w1v[8];
    #pragma unroll
    for (int j = 0; j < 8; ++j)
        w1v[j] = *(const float4*)(W1 + (size_t)m1row * HID + m1q * 32 + j * 4);
    float4 w2v[2];
    #pragma unroll
    for (int j = 0; j < 2; ++j)
        w2v[j] = *(const float4*)(W2 + (size_t)m1row * MLPH + m1q * 8 + j * 4);
    float4 w3v = make_float4(0, 0, 0, 0);
    if (tid < 256) w3v = *(const float4*)(W3 + (size_t)row3 * MLPH + q3 * 4);
    float4 wsp[4];                    // W_ih[r, 0:16) for splice dot (even lanes)
    #pragma unroll
    for (int j = 0; j < 4; ++j) wsp[j] = make_float4(0, 0, 0, 0);
    if (q == 0) {
        #pragma unroll
        for (int j = 0; j < 4; ++j) wsp[j] = *(const float4*)(W_ih + (size_t)r * D_IN + j * 4);
    }
    float bias_h = (q == 0) ? (b_ih[r] + b_hh[r]) : 0.f;
    float bias1  = (m1q == 0) ? b1[m1row] : 0.f;
    float bias2  = (m1q == 0) ? b2[m1row] : 0.f;
    float bias3  = (tid < 256 && q3 == 0) ? b3[row3] : 0.f;

    // ---- prologue: h0 = 0, x_0 staged, xcur = x_1
    const float* xb = x + (size_t)b * S_LEN * D_IN;
    if (tid < 256) s_A[0][48 + tid] = 0.f;
    if (tid < 288) ((float*)s_hp)[tid] = 0.f;   // s_hp[0][*][*]
    float4 xcur = make_float4(0, 0, 0, 0), xnxt = make_float4(0, 0, 0, 0);
    if (tid < 16) {
        float4 x0 = *(const float4*)(xb + tid * 4);
        if (tid < 4) *(float4*)&s_o[0][tid * 4] = x0;
        else         *(float4*)&s_A[0][(tid - 4) * 4] = x0;
        xcur = *(const float4*)(xb + D_IN + tid * 4);   // x_1
    }
    __syncthreads();

    float ra0, ra1, ra2, ra3;
#define RNN_CHUNKS(C0, C1)                                      \
    {                                                           \
        _Pragma("unroll")                                       \
        for (int c = (C0); c < (C1); ++c) {                     \
            float4 v = *(const float4*)(Abase + c * 4);         \
            ra0 = fmaf(wv[c].x, v.x, ra0);                      \
            ra1 = fmaf(wv[c].y, v.y, ra1);                      \
            ra2 = fmaf(wv[c].z, v.z, ra2);                      \
            ra3 = fmaf(wv[c].w, v.w, ra3);                      \
        }                                                       \
    }

    for (int t = 0; t < S_LEN; ++t) {
        const int p = t & 1;
        const float* Abase = &s_A[p][q * 152];
        ra0 = ra1 = ra2 = ra3 = 0.f;

        // ================= I1: RNN chunks 0-7 + MLP1 (o_{t-1} path) ========
        if (tid < 16) {
            int tn = (t + 2 < S_LEN) ? t + 2 : S_LEN - 1;
            xnxt = *(const float4*)(xb + (size_t)tn * D_IN + tid * 4);
        }
        RNN_CHUNKS(0, 8)
        {
            float m0 = 0.f, m1 = 0.f, m2 = 0.f, m3 = 0.f;
            const float* hp = &s_hp[p][m1q][0];
            #pragma unroll
            for (int j = 0; j < 8; ++j) {
                float4 v = *(const float4*)(hp + j * 4);
                m0 = fmaf(w1v[j].x, v.x, m0);
                m1 = fmaf(w1v[j].y, v.y, m1);
                m2 = fmaf(w1v[j].z, v.z, m2);
                m3 = fmaf(w1v[j].w, v.w, m3);
            }
            float m = (m0 + m1) + (m2 + m3);
            m += __shfl_xor(m, 1);
            m += __shfl_xor(m, 2);
            m += __shfl_xor(m, 4);
            if (m1q == 0) s_a1[m1row] = fmaxf(m + bias1, 0.f);
        }
        __syncthreads();

        // ================= I2: RNN chunks 8-17 + MLP2 + stage x[0:16) ======
        RNN_CHUNKS(8, 18)
        {
            float m0 = 0.f, m1 = 0.f;
            const float* av = &s_a1[m1q * 8];
            float4 v0 = *(const float4*)(av);
            float4 v1 = *(const float4*)(av + 4);
            m0 = fmaf(w2v[0].x, v0.x, m0);
            m0 = fmaf(w2v[0].y, v0.y, m0);
            m0 = fmaf(w2v[0].z, v0.z, m0);
            m0 = fmaf(w2v[0].w, v0.w, m0);
            m1 = fmaf(w2v[1].x, v1.x, m1);
            m1 = fmaf(w2v[1].y, v1.y, m1);
            m1 = fmaf(w2v[1].z, v1.z, m1);
            m1 = fmaf(w2v[1].w, v1.w, m1);
            float m = m0 + m1;
            m += __shfl_xor(m, 1);
            m += __shfl_xor(m, 2);
            m += __shfl_xor(m, 4);
            if (m1q == 0) s_a2[m1row] = fmaxf(m + bias2, 0.f);
        }
        if (tid < 4) *(float4*)&s_o[1 - p][tid * 4] = xcur;   // x_{t+1}[0:16)
        __syncthreads();

        // ================= I3: RNN chunks 18-29 + MLP3 -> o_{t-1} ==========
        RNN_CHUNKS(18, 30)
        if (tid < 256) {
            float4 v = *(const float4*)&s_a2[q3 * 4];
            float m = fmaf(w3v.x, v.x, 0.f);
            m = fmaf(w3v.y, v.y, m);
            m = fmaf(w3v.z, v.z, m);
            m = fmaf(w3v.w, v.w, m);
            m += __shfl_xor(m, 1);
            m += __shfl_xor(m, 2);
            m += __shfl_xor(m, 4);
            m += __shfl_xor(m, 8);
            if (q3 == 0) {
                float o = m + bias3;
                if (t > 0)  out[((size_t)b * S_LEN + (t - 1)) * D_OUT + row3] = o;
                if (t > ps) s_o[p][row3] = o;   // splice o_{t-1} into x_t[0:16)
            }
        }
        __syncthreads();

        // ================= I4: RNN chunks 30-37 + splice dot + tanh ========
        RNN_CHUNKS(30, 38)
        if (tid >= 4 && tid < 16)
            *(float4*)&s_A[1 - p][(tid - 4) * 4] = xcur;      // x_{t+1}[16:64)
        float accsum = (ra0 + ra1) + (ra2 + ra3);
        accsum += __shfl_xor(accsum, 1);                      // join K-halves
        if (q == 0) {
            float s0 = 0.f, s1 = 0.f, s2 = 0.f, s3 = 0.f;
            const float* ov = &s_o[p][0];
            float4 v0 = *(const float4*)(ov);
            float4 v1 = *(const float4*)(ov + 4);
            float4 v2 = *(const float4*)(ov + 8);
            float4 v3 = *(const float4*)(ov + 12);
            s0 = fmaf(wsp[0].x, v0.x, s0); s0 = fmaf(wsp[0].y, v0.y, s0);
            s0 = fmaf(wsp[0].z, v0.z, s0); s0 = fmaf(wsp[0].w, v0.w, s0);
            s1 = fmaf(wsp[1].x, v1.x, s1); s1 = fmaf(wsp[1].y, v1.y, s1);
            s1 = fmaf(wsp[1].z, v1.z, s1); s1 = fmaf(wsp[1].w, v1.w, s1);
            s2 = fmaf(wsp[2].x, v2.x, s2); s2 = fmaf(wsp[2].y, v2.y, s2);
            s2 = fmaf(wsp[2].z, v2.z, s2); s2 = fmaf(wsp[2].w, v2.w, s2);
            s3 = fmaf(wsp[3].x, v3.x, s3); s3 = fmaf(wsp[3].y, v3.y, s3);
            s3 = fmaf(wsp[3].z, v3.z, s3); s3 = fmaf(wsp[3].w, v3.w, s3);
            float h = fast_tanh(accsum + ((s0 + s1) + (s2 + s3)) + bias_h);
            s_A[1 - p][48 + r] = h;                 // for next RNN step
            s_hp[1 - p][r >> 5][r & 31] = h;        // padded copy for MLP1
        }
        if (tid < 16) xcur = xnxt;
        __syncthreads();
    }

    // ================= epilogue: o_{S-1} = mlp(h_S), p = 0 =================
    {
        const int p = S_LEN & 1;   // 0
        {
            float m0 = 0.f, m1 = 0.f, m2 = 0.f, m3 = 0.f;
            const float* hp = &s_hp[p][m1q][0];
            #pragma unroll
            for (int j = 0; j < 8; ++j) {
                float4 v = *(const float4*)(hp + j * 4);
                m0 = fmaf(w1v[j].x, v.x, m0);
                m1 = fmaf(w1v[j].y, v.y, m1);
                m2 = fmaf(w1v[j].z, v.z, m2);
                m3 = fmaf(w1v[j].w, v.w, m3);
            }
            float m = (m0 + m1) + (m2 + m3);
            m += __shfl_xor(m, 1);
            m += __shfl_xor(m, 2);
            m += __shfl_xor(m, 4);
            if (m1q == 0) s_a1[m1row] = fmaxf(m + bias1, 0.f);
        }
        __syncthreads();
        {
            float m0 = 0.f, m1 = 0.f;
            const float* av = &s_a1[m1q * 8];
            float4 v0 = *(const float4*)(av);
            float4 v1 = *(const float4*)(av + 4);
            m0 = fmaf(w2v[0].x, v0.x, m0);
            m0 = fmaf(w2v[0].y, v0.y, m0);
            m0 = fmaf(w2v[0].z, v0.z, m0);
            m0 = fmaf(w2v[0].w, v0.w, m0);
            m1 = fmaf(w2v[1].x, v1.x, m1);
            m1 = fmaf(w2v[1].y, v1.y, m1);
            m1 = fmaf(w2v[1].z, v1.z, m1);
            m1 = fmaf(w2v[1].w, v1.w, m1);
            float m = m0 + m1;
            m += __shfl_xor(m, 1);
            m += __shfl_xor(m, 2);
            m += __shfl_xor(m, 4);
            if (m1q == 0) s_a2[m1row] = fmaxf(m + bias2, 0.f);
        }
        __syncthreads();
        if (tid < 256) {
            float4 v = *(const float4*)&s_a2[q3 * 4];
            float m = fmaf(w3v.x, v.x, 0.f);
            m = fmaf(w3v.y, v.y, m);
            m = fmaf(w3v.z, v.z, m);
            m = fmaf(w3v.w, v.w, m);
            m += __shfl_xor(m, 1);
            m += __shfl_xor(m, 2);
            m += __shfl_xor(m, 4);
            m += __shfl_xor(m, 8);
            if (q3 == 0)
                out[((size_t)b * S_LEN + (S_LEN - 1)) * D_OUT + row3] = m + bias3;
        }
    }
#undef RNN_CHUNKS
}

extern "C" void kernel_launch(void* const* d_in, const int* in_sizes, int n_in,
                              void* d_out, int out_size, void* d_ws, size_t ws_size,
                              hipStream_t stream) {
    (void)in_sizes; (void)n_in; (void)d_ws; (void)ws_size; (void)out_size;
    const float* x    = (const float*)d_in[0];
    const float* W_ih = (const float*)d_in[1];
    const float* bih  = (const float*)d_in[2];
    const float* W_hh = (const float*)d_in[3];
    const float* bhh  = (const float*)d_in[4];
    const float* W1   = (const float*)d_in[5];
    const float* b1   = (const float*)d_in[6];
    const float* W2   = (const float*)d_in[7];
    const float* b2   = (const float*)d_in[8];
    const float* W3   = (const float*)d_in[9];
    const float* b3   = (const float*)d_in[10];
    const int*   ps   = (const int*)d_in[11];
    float* out = (float*)d_out;

    rnn_ar_kernel<<<dim3(256), dim3(512), 0, stream>>>(
        x, W_ih, bih, W_hh, bhh, W1, b1, W2, b2, W3, b3, ps, out);
}

// Round 5
// 11419.123 us; speedup vs baseline: 1.8170x; 1.8170x over previous
//
#include <hip/hip_runtime.h>
#include <hip/hip_bf16.h>

#define S_LEN 512
#define D_IN  64
#define HID   256
#define MLPH  64
#define D_OUT 16

// tanh via __expf; clamped so e stays finite. ~8 instrs, no branch.
__device__ __forceinline__ float fast_tanh(float v) {
    float a = fabsf(v);
    float e = __expf(fminf(2.0f * a, 40.0f));
    float r = __fdividef(e - 1.0f, e + 1.0f);
    return copysignf(r, v);
}

// One workgroup (1024 thr, 16 waves) per batch element, one CU each.
// Pipeline: iter t computes RNN-main_t (needs h_t, x_t[16:]) OVERLAPPED with
// MLP(h_t)=o_{t-1}; 16-wide splice dot + tanh close the step. 4 barriers/step.
// Per-thread weights ~100 floats -> fits 128 VGPRs, NO scratch spill (the
// round-4 killer: 18.5 GB/launch of spill traffic at 220 floats/thread).
__launch_bounds__(1024, 4)
__global__ void rnn_ar_kernel(const float* __restrict__ x,
                              const float* __restrict__ W_ih,
                              const float* __restrict__ b_ih,
                              const float* __restrict__ W_hh,
                              const float* __restrict__ b_hh,
                              const float* __restrict__ W1,
                              const float* __restrict__ b1,
                              const float* __restrict__ W2,
                              const float* __restrict__ b2,
                              const float* __restrict__ W3,
                              const float* __restrict__ b3,
                              const int*   __restrict__ ps_ptr,
                              float* __restrict__ out) {
    const int b   = blockIdx.x;
    const int tid = threadIdx.x;
    const int ps  = *ps_ptr;

    // roles
    const int r     = tid >> 2;       // RNN row (0..255)
    const int q     = tid & 3;        // RNN K-quarter (76 floats each)
    const int m1row = tid >> 4;       // MLP1/2 row (0..63)
    const int m1q   = tid & 15;       // MLP1/2 K-chunk (0..15)
    const int row3  = tid >> 4;       // MLP3 row (0..15) when tid<256
    const int q3    = tid & 15;       // MLP3 K-chunk

    // LDS. s_A[p] = [ x_t[16:64) (48) | h_t (256) ] combined K-vector.
    __shared__ float s_A[2][304];
    __shared__ float s_hp[2][16][20];   // h copy chunked for MLP1 (pad 20: 2-way banks, 16B-aligned)
    __shared__ float s_wsp[256][20];    // W_ih[:,0:16) padded (splice weights)
    __shared__ float s_a1[MLPH];
    __shared__ float s_a2[MLPH];
    __shared__ float s_o[2][16];        // splice zone: x_t[0:16) or o_{t-1}

    // ---- register-resident weights (~100 floats/thread)
    // RNN combined K-vector index g: g<48 -> W_ih[r][16+g], g>=48 -> W_hh[r][g-48].
    // Quarter q covers g in [q*76, q*76+76). All boundaries are float4-aligned.
    float4 wv[19];
    {
        const float* wih_r = W_ih + (size_t)r * D_IN;
        const float* whh_r = W_hh + (size_t)r * HID;
        if (q == 0) {
            #pragma unroll
            for (int j = 0; j < 12; ++j) wv[j] = *(const float4*)(wih_r + 16 + j * 4);
            #pragma unroll
            for (int j = 0; j < 7; ++j)  wv[12 + j] = *(const float4*)(whh_r + j * 4);
        } else {
            const float* base = whh_r + (q * 76 - 48);
            #pragma unroll
            for (int j = 0; j < 19; ++j) wv[j] = *(const float4*)(base + j * 4);
        }
    }
    float4 w1v[4];
    #pragma unroll
    for (int j = 0; j < 4; ++j)
        w1v[j] = *(const float4*)(W1 + (size_t)m1row * HID + m1q * 16 + j * 4);
    float4 w2v = *(const float4*)(W2 + (size_t)m1row * MLPH + m1q * 4);
    float4 w3v = make_float4(0, 0, 0, 0);
    if (tid < 256) w3v = *(const float4*)(W3 + (size_t)row3 * MLPH + q3 * 4);
    float bias_h = (q == 0) ? (b_ih[r] + b_hh[r]) : 0.f;
    float bias1  = (m1q == 0) ? b1[m1row] : 0.f;
    float bias2  = (m1q == 0) ? b2[m1row] : 0.f;
    float bias3  = (tid < 256 && q3 == 0) ? b3[row3] : 0.f;

    // ---- prologue: h0 = 0, x_0 staged, xcur = x_1, splice weights to LDS
    const float* xb = x + (size_t)b * S_LEN * D_IN;
    if (tid < 256) s_A[0][48 + tid] = 0.f;
    if (tid < 320) ((float*)s_hp)[tid] = 0.f;     // zeros s_hp[0]
    {
        int rr = tid >> 2, jj = tid & 3;          // all 1024 threads: one float4
        float4 v = *(const float4*)(W_ih + (size_t)rr * D_IN + jj * 4);
        *(float4*)&s_wsp[rr][jj * 4] = v;
    }
    float4 xcur = make_float4(0, 0, 0, 0), xnxt = make_float4(0, 0, 0, 0);
    if (tid < 16) {
        float4 x0 = *(const float4*)(xb + tid * 4);
        if (tid < 4) *(float4*)&s_o[0][tid * 4] = x0;
        else         *(float4*)&s_A[0][(tid - 4) * 4] = x0;
        xcur = *(const float4*)(xb + D_IN + tid * 4);   // x_1
    }
    __syncthreads();

    float ra0, ra1, ra2, ra3;
#define RNN_CHUNKS(C0, C1)                                      \
    {                                                           \
        _Pragma("unroll")                                       \
        for (int c = (C0); c < (C1); ++c) {                     \
            float4 v = *(const float4*)(Abase + c * 4);         \
            ra0 = fmaf(wv[c].x, v.x, ra0);                      \
            ra1 = fmaf(wv[c].y, v.y, ra1);                      \
            ra2 = fmaf(wv[c].z, v.z, ra2);                      \
            ra3 = fmaf(wv[c].w, v.w, ra3);                      \
        }                                                       \
    }

    for (int t = 0; t < S_LEN; ++t) {
        const int p = t & 1;
        const float* Abase = &s_A[p][q * 76];
        ra0 = ra1 = ra2 = ra3 = 0.f;

        // ========= I1: RNN chunks 0-4 + MLP1 (o_{t-1} path) + x prefetch ===
        if (tid < 16) {
            int tn = (t + 2 < S_LEN) ? t + 2 : S_LEN - 1;
            xnxt = *(const float4*)(xb + (size_t)tn * D_IN + tid * 4);
        }
        RNN_CHUNKS(0, 5)
        {
            float m0 = 0.f, m1 = 0.f, m2 = 0.f, m3 = 0.f;
            const float* hp = &s_hp[p][m1q][0];
            #pragma unroll
            for (int j = 0; j < 4; ++j) {
                float4 v = *(const float4*)(hp + j * 4);
                m0 = fmaf(w1v[j].x, v.x, m0);
                m1 = fmaf(w1v[j].y, v.y, m1);
                m2 = fmaf(w1v[j].z, v.z, m2);
                m3 = fmaf(w1v[j].w, v.w, m3);
            }
            float m = (m0 + m1) + (m2 + m3);
            m += __shfl_xor(m, 1);
            m += __shfl_xor(m, 2);
            m += __shfl_xor(m, 4);
            m += __shfl_xor(m, 8);
            if (m1q == 0) s_a1[m1row] = fmaxf(m + bias1, 0.f);
        }
        __syncthreads();

        // ========= I2: RNN chunks 5-10 + MLP2 + stage x_{t+1}[0:16) ========
        RNN_CHUNKS(5, 11)
        {
            float4 v0 = *(const float4*)&s_a1[m1q * 4];
            float m = fmaf(w2v.x, v0.x, 0.f);
            m = fmaf(w2v.y, v0.y, m);
            m = fmaf(w2v.z, v0.z, m);
            m = fmaf(w2v.w, v0.w, m);
            m += __shfl_xor(m, 1);
            m += __shfl_xor(m, 2);
            m += __shfl_xor(m, 4);
            m += __shfl_xor(m, 8);
            if (m1q == 0) s_a2[m1row] = fmaxf(m + bias2, 0.f);
        }
        if (tid < 4) *(float4*)&s_o[1 - p][tid * 4] = xcur;
        __syncthreads();

        // ========= I3: RNN chunks 11-15 + MLP3 -> o_{t-1}, out, splice =====
        RNN_CHUNKS(11, 16)
        if (tid < 256) {
            float4 v = *(const float4*)&s_a2[q3 * 4];
            float m = fmaf(w3v.x, v.x, 0.f);
            m = fmaf(w3v.y, v.y, m);
            m = fmaf(w3v.z, v.z, m);
            m = fmaf(w3v.w, v.w, m);
            m += __shfl_xor(m, 1);
            m += __shfl_xor(m, 2);
            m += __shfl_xor(m, 4);
            m += __shfl_xor(m, 8);
            if (q3 == 0) {
                float o = m + bias3;
                if (t > 0)  out[((size_t)b * S_LEN + (t - 1)) * D_OUT + row3] = o;
                if (t > ps) s_o[p][row3] = o;   // splice o_{t-1} into x_t[0:16)
            }
        }
        __syncthreads();

        // ========= I4: RNN chunks 16-18 + splice dot + tanh ================
        RNN_CHUNKS(16, 19)
        if (tid >= 4 && tid < 16)
            *(float4*)&s_A[1 - p][(tid - 4) * 4] = xcur;      // x_{t+1}[16:64)
        float accsum = (ra0 + ra1) + (ra2 + ra3);
        accsum += __shfl_xor(accsum, 1);                      // join 4 quarters
        accsum += __shfl_xor(accsum, 2);
        if (q == 0) {
            const float* wp = &s_wsp[r][0];
            const float* ov = &s_o[p][0];
            float s0 = 0.f, s1 = 0.f, s2 = 0.f, s3 = 0.f;
            #pragma unroll
            for (int j = 0; j < 4; ++j) {
                float4 w = *(const float4*)(wp + j * 4);
                float4 v = *(const float4*)(ov + j * 4);
                s0 = fmaf(w.x, v.x, s0);
                s1 = fmaf(w.y, v.y, s1);
                s2 = fmaf(w.z, v.z, s2);
                s3 = fmaf(w.w, v.w, s3);
            }
            float h = fast_tanh(accsum + ((s0 + s1) + (s2 + s3)) + bias_h);
            s_A[1 - p][48 + r] = h;                 // next RNN step input
            s_hp[1 - p][r >> 4][r & 15] = h;        // chunked copy for MLP1
        }
        if (tid < 16) xcur = xnxt;
        __syncthreads();
    }

    // ========= epilogue: o_{S-1} = mlp(h_S); h_S is in buffers p = 0 =======
    {
        const int p = 0;
        {
            float m0 = 0.f, m1 = 0.f, m2 = 0.f, m3 = 0.f;
            const float* hp = &s_hp[p][m1q][0];
            #pragma unroll
            for (int j = 0; j < 4; ++j) {
                float4 v = *(const float4*)(hp + j * 4);
                m0 = fmaf(w1v[j].x, v.x, m0);
                m1 = fmaf(w1v[j].y, v.y, m1);
                m2 = fmaf(w1v[j].z, v.z, m2);
                m3 = fmaf(w1v[j].w, v.w, m3);
            }
            float m = (m0 + m1) + (m2 + m3);
            m += __shfl_xor(m, 1);
            m += __shfl_xor(m, 2);
            m += __shfl_xor(m, 4);
            m += __shfl_xor(m, 8);
            if (m1q == 0) s_a1[m1row] = fmaxf(m + bias1, 0.f);
        }
        __syncthreads();
        {
            float4 v0 = *(const float4*)&s_a1[m1q * 4];
            float m = fmaf(w2v.x, v0.x, 0.f);
            m = fmaf(w2v.y, v0.y, m);
            m = fmaf(w2v.z, v0.z, m);
            m = fmaf(w2v.w, v0.w, m);
            m += __shfl_xor(m, 1);
            m += __shfl_xor(m, 2);
            m += __shfl_xor(m, 4);
            m += __shfl_xor(m, 8);
            if (m1q == 0) s_a2[m1row] = fmaxf(m + bias2, 0.f);
        }
        __syncthreads();
        if (tid < 256) {
            float4 v = *(const float4*)&s_a2[q3 * 4];
            float m = fmaf(w3v.x, v.x, 0.f);
            m = fmaf(w3v.y, v.y, m);
            m = fmaf(w3v.z, v.z, m);
            m = fmaf(w3v.w, v.w, m);
            m += __shfl_xor(m, 1);
            m += __shfl_xor(m, 2);
            m += __shfl_xor(m, 4);
            m += __shfl_xor(m, 8);
            if (q3 == 0)
                out[((size_t)b * S_LEN + (S_LEN - 1)) * D_OUT + row3] = m + bias3;
        }
    }
#undef RNN_CHUNKS
}

extern "C" void kernel_launch(void* const* d_in, const int* in_sizes, int n_in,
                              void* d_out, int out_size, void* d_ws, size_t ws_size,
                              hipStream_t stream) {
    (void)in_sizes; (void)n_in; (void)d_ws; (void)ws_size; (void)out_size;
    const float* x    = (const float*)d_in[0];
    const float* W_ih = (const float*)d_in[1];
    const float* bih  = (const float*)d_in[2];
    const float* W_hh = (const float*)d_in[3];
    const float* bhh  = (const float*)d_in[4];
    const float* W1   = (const float*)d_in[5];
    const float* b1   = (const float*)d_in[6];
    const float* W2   = (const float*)d_in[7];
    const float* b2   = (const float*)d_in[8];
    const float* W3   = (const float*)d_in[9];
    const float* b3   = (const float*)d_in[10];
    const int*   ps   = (const int*)d_in[11];
    float* out = (float*)d_out;

    rnn_ar_kernel<<<dim3(256), dim3(1024), 0, stream>>>(
        x, W_ih, bih, W_hh, bhh, W1, b1, W2, b2, W3, b3, ps, out);
}